// Round 6
// baseline (486.295 us; speedup 1.0000x reference)
//
#include <hip/hip_runtime.h>
#include <hip/hip_bf16.h>

#define KK 7
#define NL1 8
#define NL2 8
#define BLK 8
#define IMG 128
#define NBLK 16          // blocks per spatial dim
#define TILE_O1 14       // BLK + 2*(K/2)
#define TILE_X 20        // BLK + 4*(K/2)
#define NBINS 64

__global__ __launch_bounds__(64) void pcanet_fused(
    const float* __restrict__ x,    // (32,3,128,128)
    const float* __restrict__ w1,   // (8,3,7,7)
    const float* __restrict__ w2,   // (8,1,7,7)
    float* __restrict__ out)        // (32, 8*256*64)
{
    const int tid = threadIdx.x;        // 0..63
    const int blk = blockIdx.x;         // 0..255 : bp*16 + bq
    const int ch  = blockIdx.y;         // L1 filter index
    const int n   = blockIdx.z;         // image index
    const int bp  = blk >> 4;
    const int bq  = blk & 15;
    const int P0  = bp * BLK;           // block origin, first spatial dim
    const int Q0  = bq * BLK;           // block origin, second spatial dim

    __shared__ float xt[3][TILE_X][TILE_X];     // x tile, zero-padded
    __shared__ float o1[TILE_O1][TILE_O1];      // conv1 tile, f32-materialized
    __shared__ float w1t[3][KK][KK];
    __shared__ float w2t[NL2][KK][KK];
    __shared__ int   hist[NBINS];

    // ---- load filters ----
    for (int i = tid; i < 3 * KK * KK; i += 64)
        ((float*)w1t)[i] = w1[ch * 3 * KK * KK + i];
    for (int i = tid; i < NL2 * KK * KK; i += 64)
        ((float*)w2t)[i] = w2[i];

    // ---- load x tile with zero padding ----
    const float* xn = x + (size_t)n * 3 * IMG * IMG;
    for (int i = tid; i < 3 * TILE_X * TILE_X; i += 64) {
        int c   = i / (TILE_X * TILE_X);
        int rem = i % (TILE_X * TILE_X);
        int r   = rem / TILE_X;
        int s   = rem % TILE_X;
        int gr  = P0 - 6 + r;
        int gs  = Q0 - 6 + s;
        float v = 0.0f;
        if (gr >= 0 && gr < IMG && gs >= 0 && gs < IMG)
            v = xn[((size_t)c * IMG + gr) * IMG + gs];
        xt[c][r][s] = v;
    }
    if (tid < NBINS) hist[tid] = 0;
    __syncthreads();

    // ---- conv1: f32, Eigen gebp model — strict sequential K reduction, ----
    // ---- K laid out channels-fastest: k = (kh*7 + kw)*3 + c, fused FMA ----
    // Zero taps: fmaf(0, w, acc) == acc exactly -> zero-filled tile is
    // bit-identical to reference zero-padding.
    for (int i = tid; i < TILE_O1 * TILE_O1; i += 64) {
        int r  = i / TILE_O1;
        int s  = i % TILE_O1;
        int gr = P0 - 3 + r;
        int gs = Q0 - 3 + s;
        float acc = 0.0f;
        if (gr >= 0 && gr < IMG && gs >= 0 && gs < IMG) {
            for (int dp = 0; dp < KK; ++dp)          // kh slowest
                for (int dq = 0; dq < KK; ++dq)      // kw middle
                    for (int c = 0; c < 3; ++c)      // channel fastest
                        acc = __builtin_fmaf(xt[c][r + dp][s + dq], w1t[c][dp][dq], acc);
        }
        o1[r][s] = acc;   // f32 materialization point (matches reference)
    }
    __syncthreads();

    // ---- conv2: f32 sequential FMA, (kh, kw) with kw fastest (C=1) ----
    const int i2 = tid >> 3;    // row within 8x8 block
    const int j2 = tid & 7;     // col within 8x8 block
    int code = 0;
    for (int l = 0; l < NL2; ++l) {
        float acc = 0.0f;
        for (int dp = 0; dp < KK; ++dp)
            for (int dq = 0; dq < KK; ++dq)
                acc = __builtin_fmaf(o1[i2 + dp][j2 + dq], w2t[l][dp][dq], acc);
        if (acc > 0.0f) code |= (1 << l);
    }

    // ---- per-block 64-bin histogram (bin width DIV=4) ----
    atomicAdd(&hist[code >> 2], 1);
    __syncthreads();

    size_t base = (((size_t)n * NL1 + ch) * (NBLK * NBLK) + blk) * NBINS;
    out[base + tid] = (float)hist[tid];
}

extern "C" void kernel_launch(void* const* d_in, const int* in_sizes, int n_in,
                              void* d_out, int out_size, void* d_ws, size_t ws_size,
                              hipStream_t stream) {
    const float* x  = (const float*)d_in[0];
    const float* w1 = (const float*)d_in[1];
    const float* w2 = (const float*)d_in[2];
    float* out = (float*)d_out;

    dim3 grid(NBLK * NBLK, NL1, 32);   // (256 blocks, 8 L1 channels, 32 images)
    dim3 block(64);
    pcanet_fused<<<grid, block, 0, stream>>>(x, w1, w2, out);
}

// Round 7
// 335.382 us; speedup vs baseline: 1.4500x; 1.4500x over previous
//
#include <hip/hip_runtime.h>
#include <hip/hip_bf16.h>

#define KK 7
#define NL1 8
#define NL2 8
#define IMG 128
#define REG 32            // region edge (pixels) per workgroup
#define RT 38             // o1 tile edge = REG + 6
#define O1P 40            // o1 padded pitch (floats), 160 B (16B-aligned rows)
#define XR 44             // xt real rows/cols = REG + 12
#define XTP 48            // xt padded pitch (floats), 192 B (16B-aligned rows)
#define NBINS 64
#define NHB 16            // histogram blocks per region (4x4 of 8x8)

// Correctness contract (matches XLA-CPU f32 reference, verified round 6):
//  conv1: per-pixel strict sequential FMA chain, taps ordered dp->dq->c(fastest)
//  out1 : materialized as f32
//  conv2: per-filter strict sequential FMA chain, taps ordered dp->dq
// Any restructuring below only changes WHERE operands come from (registers vs
// LDS) and how much work runs in parallel across pixels/filters — never the
// per-accumulator operation sequence.

__global__ __launch_bounds__(256, 3) void pcanet_fused(
    const float* __restrict__ x,    // (32,3,128,128)
    const float* __restrict__ w1,   // (8,3,7,7)
    const float* __restrict__ w2,   // (8,1,7,7)
    float* __restrict__ out)        // (32, 8*256*64)
{
    const int tid = threadIdx.x;        // 0..255
    const int reg = blockIdx.x;         // 0..15 : 4x4 regions
    const int ch  = blockIdx.y;         // L1 filter index
    const int n   = blockIdx.z;         // image index
    const int P0  = (reg >> 2) * REG;   // region row origin
    const int Q0  = (reg & 3) * REG;    // region col origin

    __shared__ __align__(16) float xt[3][XR][XTP];   // zero-padded x tile
    __shared__ __align__(16) float o1[RT][O1P];      // f32-materialized conv1 tile
    __shared__ __align__(16) float w1t[KK][24];      // [dp][dq*3+c] (+3 pad)
    __shared__ __align__(16) float w2t[KK][56];      // [dp][l*7+dq]
    __shared__ int hist[NHB * NBINS];

    // ---- filter relayout (per-dp rows become contiguous b128-loadable) ----
    for (int i = tid; i < 3 * KK * KK; i += 256) {
        int c = i / 49, rem = i % 49, dp = rem / 7, dq = rem % 7;
        w1t[dp][dq * 3 + c] = w1[ch * 147 + i];
    }
    for (int i = tid; i < NL2 * KK * KK; i += 256) {
        int l = i / 49, rem = i % 49, dp = rem / 7, dq = rem % 7;
        w2t[dp][l * 7 + dq] = w2[i];
    }
    // pad cols of w1t rows (never multiplied, but keep defined)
    for (int i = tid; i < KK * 3; i += 256) w1t[i / 3][21 + (i % 3)] = 0.f;

    // ---- x tile fill, zero-padded (cols >= XR and out-of-image -> 0) ----
    const float* xn = x + (size_t)n * 3 * IMG * IMG;
    for (int i = tid; i < 3 * XR * XTP; i += 256) {
        int c = i / (XR * XTP), rem = i % (XR * XTP), r = rem / XTP, s = rem % XTP;
        int gr = P0 - 6 + r, gs = Q0 - 6 + s;
        float v = 0.0f;
        if (s < XR && gr >= 0 && gr < IMG && gs >= 0 && gs < IMG)
            v = xn[((size_t)c * IMG + gr) * IMG + gs];
        xt[c][r][s] = v;
    }
    for (int i = tid; i < NHB * NBINS; i += 256) hist[i] = 0;
    __syncthreads();

    // ---- conv1: 38 rows x 10 col-chunks(of 4) = 380 tasks, 2 passes ----
    for (int it = 0; it < 2; ++it) {
        int task = tid + it * 256;
        if (task < 380) {
            int r1 = task / 10;            // o1 tile row 0..37
            int c1 = 4 * (task % 10);      // o1 tile col base 0..36 (16B-aligned)
            float a0 = 0.f, a1 = 0.f, a2 = 0.f, a3 = 0.f;
            for (int dp = 0; dp < KK; ++dp) {
                float wr[24];
                {
                    const float4* wsrc = (const float4*)&w1t[dp][0];
                    #pragma unroll
                    for (int q = 0; q < 6; ++q) ((float4*)wr)[q] = wsrc[q];
                }
                float fx[3][12];
                #pragma unroll
                for (int c = 0; c < 3; ++c) {
                    const float4* fsrc = (const float4*)&xt[c][r1 + dp][c1];
                    #pragma unroll
                    for (int q = 0; q < 3; ++q) ((float4*)fx[c])[q] = fsrc[q];
                }
                #pragma unroll
                for (int dq = 0; dq < KK; ++dq)
                    #pragma unroll
                    for (int c = 0; c < 3; ++c) {
                        float w = wr[dq * 3 + c];
                        a0 = __builtin_fmaf(fx[c][0 + dq], w, a0);
                        a1 = __builtin_fmaf(fx[c][1 + dq], w, a1);
                        a2 = __builtin_fmaf(fx[c][2 + dq], w, a2);
                        a3 = __builtin_fmaf(fx[c][3 + dq], w, a3);
                    }
            }
            // mask out-of-image o1 pixels to exact 0 (conv2's zero padding)
            int gr = P0 - 3 + r1;
            bool rok = (gr >= 0 && gr < IMG);
            float4 st;
            int gs0 = Q0 - 3 + c1;
            st.x = (rok && gs0 + 0 >= 0 && gs0 + 0 < IMG) ? a0 : 0.f;
            st.y = (rok && gs0 + 1 >= 0 && gs0 + 1 < IMG) ? a1 : 0.f;
            st.z = (rok && gs0 + 2 >= 0 && gs0 + 2 < IMG) ? a2 : 0.f;
            st.w = (rok && gs0 + 3 >= 0 && gs0 + 3 < IMG) ? a3 : 0.f;
            *(float4*)&o1[r1][c1] = st;   // cols 38/39 of chunk 9 are unread pad
        }
    }
    __syncthreads();

    // ---- conv2: thread owns 4 adjacent pixels (r, c0..c0+3) ----
    {
        const int r  = tid >> 3;          // 0..31 output row in region
        const int c0 = (tid & 7) * 4;     // 0..28 output col base (16B-aligned)
        float acc[NL2][4];
        #pragma unroll
        for (int l = 0; l < NL2; ++l)
            #pragma unroll
            for (int k = 0; k < 4; ++k) acc[l][k] = 0.f;

        for (int dp = 0; dp < KK; ++dp) {
            float wr[56];
            {
                const float4* wsrc = (const float4*)&w2t[dp][0];
                #pragma unroll
                for (int q = 0; q < 14; ++q) ((float4*)wr)[q] = wsrc[q];
            }
            float f[12];
            {
                const float4* fsrc = (const float4*)&o1[r + dp][c0];
                #pragma unroll
                for (int q = 0; q < 3; ++q) ((float4*)f)[q] = fsrc[q];
            }
            #pragma unroll
            for (int l = 0; l < NL2; ++l)
                #pragma unroll
                for (int dq = 0; dq < KK; ++dq) {
                    float w = wr[l * 7 + dq];
                    acc[l][0] = __builtin_fmaf(f[0 + dq], w, acc[l][0]);
                    acc[l][1] = __builtin_fmaf(f[1 + dq], w, acc[l][1]);
                    acc[l][2] = __builtin_fmaf(f[2 + dq], w, acc[l][2]);
                    acc[l][3] = __builtin_fmaf(f[3 + dq], w, acc[l][3]);
                }
        }
        #pragma unroll
        for (int k = 0; k < 4; ++k) {
            int code = 0;
            #pragma unroll
            for (int l = 0; l < NL2; ++l)
                if (acc[l][k] > 0.0f) code |= (1 << l);
            int bc = (c0 + k) >> 3, br = r >> 3;
            atomicAdd(&hist[(br * 4 + bc) * NBINS + (code >> 2)], 1);
        }
    }
    __syncthreads();

    // ---- write out 16 blocks x 64 bins ----
    size_t planeBase = ((size_t)(n * NL1 + ch)) * 256 * NBINS;
    for (int i = tid; i < NHB * NBINS; i += 256) {
        int bl = i >> 6, bin = i & 63;
        int br = bl >> 2, bc = bl & 3;
        int blkg = ((P0 >> 3) + br) * 16 + ((Q0 >> 3) + bc);
        out[planeBase + (size_t)blkg * NBINS + bin] = (float)hist[i];
    }
}

extern "C" void kernel_launch(void* const* d_in, const int* in_sizes, int n_in,
                              void* d_out, int out_size, void* d_ws, size_t ws_size,
                              hipStream_t stream) {
    const float* x  = (const float*)d_in[0];
    const float* w1 = (const float*)d_in[1];
    const float* w2 = (const float*)d_in[2];
    float* out = (float*)d_out;

    dim3 grid(16, NL1, 32);   // (4x4 regions, 8 L1 channels, 32 images)
    dim3 block(256);
    pcanet_fused<<<grid, block, 0, stream>>>(x, w1, w2, out);
}

// Round 8
// 123.334 us; speedup vs baseline: 3.9429x; 2.7193x over previous
//
#include <hip/hip_runtime.h>
#include <hip/hip_bf16.h>

#define KK 7
#define NL1 8
#define NL2 8
#define IMG 128
#define REG 32            // region edge (pixels) per workgroup
#define RT 38             // o1 tile edge = REG + 6
#define O1P 40            // o1 padded pitch (floats), 160 B (16B-aligned rows)
#define XR 44             // xt real rows/cols = REG + 12
#define XTP 48            // xt padded pitch (floats), 192 B (16B-aligned rows)
#define NBINS 64
#define NHB 16            // histogram blocks per region (4x4 of 8x8)

// Correctness contract (matches XLA-CPU f32 reference, verified round 6):
//  conv1: per-pixel strict sequential FMA chain, taps ordered dp->dq->c(fastest)
//  out1 : materialized as f32 (and zeroed outside the image = conv2 padding)
//  conv2: per-filter strict sequential FMA chain, taps ordered dp->dq
// Restructuring only changes WHERE operands come from, never per-chain order.
//
// Round-8 change: no address-taken local arrays (rule #20 — they spilled to
// scratch: 1.3 GB/dispatch HBM traffic in round 7). f[] filled element-wise
// from float4 temps; weights read as wave-uniform scalar loads (SGPR operand).

#define LDX12(dst, plane, row, col)                                          \
    { float4 t_;                                                             \
      t_ = *(const float4*)&xt[plane][row][col];                             \
      dst[0]=t_.x; dst[1]=t_.y; dst[2]=t_.z; dst[3]=t_.w;                    \
      t_ = *(const float4*)&xt[plane][row][(col)+4];                         \
      dst[4]=t_.x; dst[5]=t_.y; dst[6]=t_.z; dst[7]=t_.w;                    \
      t_ = *(const float4*)&xt[plane][row][(col)+8];                         \
      dst[8]=t_.x; dst[9]=t_.y; dst[10]=t_.z; dst[11]=t_.w; }

__global__ __launch_bounds__(256, 2) void pcanet_fused(
    const float* __restrict__ x,    // (32,3,128,128)
    const float* __restrict__ w1,   // (8,3,7,7)
    const float* __restrict__ w2,   // (8,1,7,7)
    float* __restrict__ out)        // (32, 8*256*64)
{
    const int tid = threadIdx.x;        // 0..255
    const int reg = blockIdx.x;         // 0..15 : 4x4 regions
    const int ch  = blockIdx.y;         // L1 filter index
    const int n   = blockIdx.z;         // image index
    const int P0  = (reg >> 2) * REG;   // region row origin
    const int Q0  = (reg & 3) * REG;    // region col origin

    __shared__ __align__(16) float xt[3][XR][XTP];   // zero-padded x tile
    __shared__ __align__(16) float o1[RT][O1P];      // f32-materialized conv1 tile
    __shared__ int hist[NHB * NBINS];

    const float* __restrict__ w1g = w1 + ch * 147;   // wave-uniform -> s_load
    const float* __restrict__ w2g = w2;              // wave-uniform -> s_load

    // ---- x tile fill, zero-padded (cols >= XR and out-of-image -> 0) ----
    const float* xn = x + (size_t)n * 3 * IMG * IMG;
    for (int i = tid; i < 3 * XR * XTP; i += 256) {
        int c = i / (XR * XTP), rem = i % (XR * XTP), r = rem / XTP, s = rem % XTP;
        int gr = P0 - 6 + r, gs = Q0 - 6 + s;
        float v = 0.0f;
        if (s < XR && gr >= 0 && gr < IMG && gs >= 0 && gs < IMG)
            v = xn[((size_t)c * IMG + gr) * IMG + gs];
        xt[c][r][s] = v;
    }
    for (int i = tid; i < NHB * NBINS; i += 256) hist[i] = 0;
    __syncthreads();

    // ---- conv1: 38 rows x 10 col-chunks(of 4) = 380 tasks, 2 passes ----
    for (int it = 0; it < 2; ++it) {
        int task = tid + it * 256;
        if (task < 380) {
            int r1 = task / 10;            // o1 tile row 0..37
            int c1 = 4 * (task % 10);      // o1 tile col base 0..36 (16B-aligned)
            float a0 = 0.f, a1 = 0.f, a2 = 0.f, a3 = 0.f;
            for (int dp = 0; dp < KK; ++dp) {
                float f0[12], f1[12], f2[12];
                LDX12(f0, 0, r1 + dp, c1)
                LDX12(f1, 1, r1 + dp, c1)
                LDX12(f2, 2, r1 + dp, c1)
                #pragma unroll
                for (int dq = 0; dq < KK; ++dq) {
                    float wa = w1g[dp * 7 + dq];           // c = 0
                    float wb = w1g[49 + dp * 7 + dq];      // c = 1
                    float wc = w1g[98 + dp * 7 + dq];      // c = 2
                    a0 = __builtin_fmaf(f0[dq + 0], wa, a0);
                    a0 = __builtin_fmaf(f1[dq + 0], wb, a0);
                    a0 = __builtin_fmaf(f2[dq + 0], wc, a0);
                    a1 = __builtin_fmaf(f0[dq + 1], wa, a1);
                    a1 = __builtin_fmaf(f1[dq + 1], wb, a1);
                    a1 = __builtin_fmaf(f2[dq + 1], wc, a1);
                    a2 = __builtin_fmaf(f0[dq + 2], wa, a2);
                    a2 = __builtin_fmaf(f1[dq + 2], wb, a2);
                    a2 = __builtin_fmaf(f2[dq + 2], wc, a2);
                    a3 = __builtin_fmaf(f0[dq + 3], wa, a3);
                    a3 = __builtin_fmaf(f1[dq + 3], wb, a3);
                    a3 = __builtin_fmaf(f2[dq + 3], wc, a3);
                }
            }
            // mask out-of-image o1 pixels to exact 0 (conv2's zero padding)
            int gr  = P0 - 3 + r1;
            int gs0 = Q0 - 3 + c1;
            bool rok = (gr >= 0 && gr < IMG);
            float4 st;
            st.x = (rok && gs0 + 0 >= 0 && gs0 + 0 < IMG) ? a0 : 0.f;
            st.y = (rok && gs0 + 1 >= 0 && gs0 + 1 < IMG) ? a1 : 0.f;
            st.z = (rok && gs0 + 2 >= 0 && gs0 + 2 < IMG) ? a2 : 0.f;
            st.w = (rok && gs0 + 3 >= 0 && gs0 + 3 < IMG) ? a3 : 0.f;
            *(float4*)&o1[r1][c1] = st;   // cols 38/39 of chunk 9 are unread pad
        }
    }
    __syncthreads();

    // ---- conv2: thread owns 4 adjacent pixels (r, c0..c0+3) ----
    {
        const int r  = tid >> 3;          // 0..31 output row in region
        const int c0 = (tid & 7) * 4;     // 0..28 output col base (16B-aligned)
        float acc[NL2][4];
        #pragma unroll
        for (int l = 0; l < NL2; ++l)
            #pragma unroll
            for (int k = 0; k < 4; ++k) acc[l][k] = 0.f;

        for (int dp = 0; dp < KK; ++dp) {
            float f[12];
            { float4 t_;
              t_ = *(const float4*)&o1[r + dp][c0];
              f[0]=t_.x; f[1]=t_.y; f[2]=t_.z; f[3]=t_.w;
              t_ = *(const float4*)&o1[r + dp][c0 + 4];
              f[4]=t_.x; f[5]=t_.y; f[6]=t_.z; f[7]=t_.w;
              t_ = *(const float4*)&o1[r + dp][c0 + 8];
              f[8]=t_.x; f[9]=t_.y; f[10]=t_.z; f[11]=t_.w; }
            #pragma unroll
            for (int l = 0; l < NL2; ++l)
                #pragma unroll
                for (int dq = 0; dq < KK; ++dq) {
                    float w = w2g[l * 49 + dp * 7 + dq];   // uniform scalar
                    acc[l][0] = __builtin_fmaf(f[dq + 0], w, acc[l][0]);
                    acc[l][1] = __builtin_fmaf(f[dq + 1], w, acc[l][1]);
                    acc[l][2] = __builtin_fmaf(f[dq + 2], w, acc[l][2]);
                    acc[l][3] = __builtin_fmaf(f[dq + 3], w, acc[l][3]);
                }
        }
        #pragma unroll
        for (int k = 0; k < 4; ++k) {
            int code = 0;
            #pragma unroll
            for (int l = 0; l < NL2; ++l)
                if (acc[l][k] > 0.0f) code |= (1 << l);
            int bc = (c0 + k) >> 3, br = r >> 3;
            atomicAdd(&hist[(br * 4 + bc) * NBINS + (code >> 2)], 1);
        }
    }
    __syncthreads();

    // ---- write out 16 blocks x 64 bins ----
    size_t planeBase = ((size_t)(n * NL1 + ch)) * 256 * NBINS;
    for (int i = tid; i < NHB * NBINS; i += 256) {
        int bl = i >> 6, bin = i & 63;
        int br = bl >> 2, bc = bl & 3;
        int blkg = ((P0 >> 3) + br) * 16 + ((Q0 >> 3) + bc);
        out[planeBase + (size_t)blkg * NBINS + bin] = (float)hist[i];
    }
}

extern "C" void kernel_launch(void* const* d_in, const int* in_sizes, int n_in,
                              void* d_out, int out_size, void* d_ws, size_t ws_size,
                              hipStream_t stream) {
    const float* x  = (const float*)d_in[0];
    const float* w1 = (const float*)d_in[1];
    const float* w2 = (const float*)d_in[2];
    float* out = (float*)d_out;

    dim3 grid(16, NL1, 32);   // (4x4 regions, 8 L1 channels, 32 images)
    dim3 block(256);
    pcanet_fused<<<grid, block, 0, stream>>>(x, w1, w2, out);
}

// Round 9
// 114.694 us; speedup vs baseline: 4.2399x; 1.0753x over previous
//
#include <hip/hip_runtime.h>
#include <hip/hip_bf16.h>

#define KK 7
#define NL1 8
#define NL2 8
#define IMG 128
#define REG 32            // region edge (pixels) per workgroup
#define RT 38             // o1 tile edge = REG + 6
#define O1P 44            // o1 padded pitch: 176B, 16B-aligned, mod-32-banks = 12
#define XR 44             // xt real rows/cols = REG + 12
#define XTP 52            // xt padded pitch: 208B, 16B-aligned, mod-32-banks = 20
#define NBINS 64
#define HSTRIDE 65        // hist pitch in ints (decorrelate block bases)
#define NHB 16            // histogram blocks per region (4x4 of 8x8)

// Correctness contract (matches XLA-CPU f32 reference, verified round 6):
//  conv1: per-pixel strict sequential FMA chain, taps ordered dp->dq->c(fastest)
//  out1 : materialized as f32 (and zeroed outside the image = conv2 padding)
//  conv2: per-filter strict sequential FMA chain, taps ordered dp->dq
// Restructuring only changes WHERE operands come from, never per-chain order.
//
// Round-9 change: bank-conflict-free pitches (XTP 48->52, O1P 40->44, hist
// stride 65). Round-8's pitches put rows 2 (resp. 4) apart on identical banks
// -> 3.03e7 conflict cycles/dispatch.

#define LDX12(dst, plane, row, col)                                          \
    { float4 t_;                                                             \
      t_ = *(const float4*)&xt[plane][row][col];                             \
      dst[0]=t_.x; dst[1]=t_.y; dst[2]=t_.z; dst[3]=t_.w;                    \
      t_ = *(const float4*)&xt[plane][row][(col)+4];                         \
      dst[4]=t_.x; dst[5]=t_.y; dst[6]=t_.z; dst[7]=t_.w;                    \
      t_ = *(const float4*)&xt[plane][row][(col)+8];                         \
      dst[8]=t_.x; dst[9]=t_.y; dst[10]=t_.z; dst[11]=t_.w; }

__global__ __launch_bounds__(256, 4) void pcanet_fused(
    const float* __restrict__ x,    // (32,3,128,128)
    const float* __restrict__ w1,   // (8,3,7,7)
    const float* __restrict__ w2,   // (8,1,7,7)
    float* __restrict__ out)        // (32, 8*256*64)
{
    const int tid = threadIdx.x;        // 0..255
    const int reg = blockIdx.x;         // 0..15 : 4x4 regions
    const int ch  = blockIdx.y;         // L1 filter index
    const int n   = blockIdx.z;         // image index
    const int P0  = (reg >> 2) * REG;   // region row origin
    const int Q0  = (reg & 3) * REG;    // region col origin

    __shared__ __align__(16) float xt[3][XR][XTP];   // zero-padded x tile
    __shared__ __align__(16) float o1[RT][O1P];      // f32-materialized conv1 tile
    __shared__ int hist[NHB * HSTRIDE];

    const float* __restrict__ w1g = w1 + ch * 147;   // wave-uniform -> s_load
    const float* __restrict__ w2g = w2;              // wave-uniform -> s_load

    // ---- x tile fill, zero-padded (cols >= XR and out-of-image -> 0) ----
    const float* xn = x + (size_t)n * 3 * IMG * IMG;
    for (int i = tid; i < 3 * XR * XTP; i += 256) {
        int c = i / (XR * XTP), rem = i % (XR * XTP), r = rem / XTP, s = rem % XTP;
        int gr = P0 - 6 + r, gs = Q0 - 6 + s;
        float v = 0.0f;
        if (s < XR && gr >= 0 && gr < IMG && gs >= 0 && gs < IMG)
            v = xn[((size_t)c * IMG + gr) * IMG + gs];
        xt[c][r][s] = v;
    }
    for (int i = tid; i < NHB * HSTRIDE; i += 256) hist[i] = 0;
    __syncthreads();

    // ---- conv1: 38 rows x 10 col-chunks(of 4) = 380 tasks, 2 passes ----
    for (int it = 0; it < 2; ++it) {
        int task = tid + it * 256;
        if (task < 380) {
            int r1 = task / 10;            // o1 tile row 0..37
            int c1 = 4 * (task % 10);      // o1 tile col base 0..36 (16B-aligned)
            float a0 = 0.f, a1 = 0.f, a2 = 0.f, a3 = 0.f;
            for (int dp = 0; dp < KK; ++dp) {
                float f0[12], f1[12], f2[12];
                LDX12(f0, 0, r1 + dp, c1)
                LDX12(f1, 1, r1 + dp, c1)
                LDX12(f2, 2, r1 + dp, c1)
                #pragma unroll
                for (int dq = 0; dq < KK; ++dq) {
                    float wa = w1g[dp * 7 + dq];           // c = 0
                    float wb = w1g[49 + dp * 7 + dq];      // c = 1
                    float wc = w1g[98 + dp * 7 + dq];      // c = 2
                    a0 = __builtin_fmaf(f0[dq + 0], wa, a0);
                    a0 = __builtin_fmaf(f1[dq + 0], wb, a0);
                    a0 = __builtin_fmaf(f2[dq + 0], wc, a0);
                    a1 = __builtin_fmaf(f0[dq + 1], wa, a1);
                    a1 = __builtin_fmaf(f1[dq + 1], wb, a1);
                    a1 = __builtin_fmaf(f2[dq + 1], wc, a1);
                    a2 = __builtin_fmaf(f0[dq + 2], wa, a2);
                    a2 = __builtin_fmaf(f1[dq + 2], wb, a2);
                    a2 = __builtin_fmaf(f2[dq + 2], wc, a2);
                    a3 = __builtin_fmaf(f0[dq + 3], wa, a3);
                    a3 = __builtin_fmaf(f1[dq + 3], wb, a3);
                    a3 = __builtin_fmaf(f2[dq + 3], wc, a3);
                }
            }
            // mask out-of-image o1 pixels to exact 0 (conv2's zero padding)
            int gr  = P0 - 3 + r1;
            int gs0 = Q0 - 3 + c1;
            bool rok = (gr >= 0 && gr < IMG);
            float4 st;
            st.x = (rok && gs0 + 0 >= 0 && gs0 + 0 < IMG) ? a0 : 0.f;
            st.y = (rok && gs0 + 1 >= 0 && gs0 + 1 < IMG) ? a1 : 0.f;
            st.z = (rok && gs0 + 2 >= 0 && gs0 + 2 < IMG) ? a2 : 0.f;
            st.w = (rok && gs0 + 3 >= 0 && gs0 + 3 < IMG) ? a3 : 0.f;
            *(float4*)&o1[r1][c1] = st;   // cols 38/39 of chunk 9 are unread pad
        }
    }
    __syncthreads();

    // ---- conv2: thread owns 4 adjacent pixels (r, c0..c0+3) ----
    {
        const int r  = tid >> 3;          // 0..31 output row in region
        const int c0 = (tid & 7) * 4;     // 0..28 output col base (16B-aligned)
        float acc[NL2][4];
        #pragma unroll
        for (int l = 0; l < NL2; ++l)
            #pragma unroll
            for (int k = 0; k < 4; ++k) acc[l][k] = 0.f;

        for (int dp = 0; dp < KK; ++dp) {
            float f[12];
            { float4 t_;
              t_ = *(const float4*)&o1[r + dp][c0];
              f[0]=t_.x; f[1]=t_.y; f[2]=t_.z; f[3]=t_.w;
              t_ = *(const float4*)&o1[r + dp][c0 + 4];
              f[4]=t_.x; f[5]=t_.y; f[6]=t_.z; f[7]=t_.w;
              t_ = *(const float4*)&o1[r + dp][c0 + 8];
              f[8]=t_.x; f[9]=t_.y; f[10]=t_.z; f[11]=t_.w; }
            #pragma unroll
            for (int l = 0; l < NL2; ++l)
                #pragma unroll
                for (int dq = 0; dq < KK; ++dq) {
                    float w = w2g[l * 49 + dp * 7 + dq];   // uniform scalar
                    acc[l][0] = __builtin_fmaf(f[dq + 0], w, acc[l][0]);
                    acc[l][1] = __builtin_fmaf(f[dq + 1], w, acc[l][1]);
                    acc[l][2] = __builtin_fmaf(f[dq + 2], w, acc[l][2]);
                    acc[l][3] = __builtin_fmaf(f[dq + 3], w, acc[l][3]);
                }
        }
        #pragma unroll
        for (int k = 0; k < 4; ++k) {
            int code = 0;
            #pragma unroll
            for (int l = 0; l < NL2; ++l)
                if (acc[l][k] > 0.0f) code |= (1 << l);
            int bc = (c0 + k) >> 3, br = r >> 3;
            atomicAdd(&hist[(br * 4 + bc) * HSTRIDE + (code >> 2)], 1);
        }
    }
    __syncthreads();

    // ---- write out 16 blocks x 64 bins ----
    size_t planeBase = ((size_t)(n * NL1 + ch)) * 256 * NBINS;
    for (int i = tid; i < NHB * NBINS; i += 256) {
        int bl = i >> 6, bin = i & 63;
        int br = bl >> 2, bc = bl & 3;
        int blkg = ((P0 >> 3) + br) * 16 + ((Q0 >> 3) + bc);
        out[planeBase + (size_t)blkg * NBINS + bin] = (float)hist[bl * HSTRIDE + bin];
    }
}

extern "C" void kernel_launch(void* const* d_in, const int* in_sizes, int n_in,
                              void* d_out, int out_size, void* d_ws, size_t ws_size,
                              hipStream_t stream) {
    const float* x  = (const float*)d_in[0];
    const float* w1 = (const float*)d_in[1];
    const float* w2 = (const float*)d_in[2];
    float* out = (float*)d_out;

    dim3 grid(16, NL1, 32);   // (4x4 regions, 8 L1 channels, 32 images)
    dim3 block(256);
    pcanet_fused<<<grid, block, 0, stream>>>(x, w1, w2, out);
}

// Round 10
// 96.238 us; speedup vs baseline: 5.0530x; 1.1918x over previous
//
#include <hip/hip_runtime.h>
#include <hip/hip_bf16.h>

#define KK 7
#define NL1 8
#define NL2 8
#define IMG 128
#define REG 32            // region edge (pixels) per workgroup
#define RT 38             // o1 tile edge = REG + 6
#define O1P 44            // o1 padded pitch (176B, 16B-aligned)
#define XR 44             // xt real rows/cols = REG + 12
#define XTP 52            // xt padded pitch (208B, 16B-aligned)
#define NBINS 64
#define HSTRIDE 65        // hist pitch in ints
#define NHB 16            // histogram blocks per region (4x4 of 8x8)

// Correctness contract (matches XLA-CPU f32 reference, verified round 6):
//  conv1: per-pixel strict sequential FMA chain, taps ordered dp->dq->c(fastest)
//  out1 : materialized as f32 (and zeroed outside the image = conv2 padding)
//  conv2: per-filter strict sequential FMA chain, taps ordered dp->dq
// Restructuring only changes WHERE operands come from, never per-chain order.
//
// Round-10: (a) row-paired conv1 — one x-row load feeds dp=e of row0 and
// dp=e-1 of row1 (each accumulator still sees dp strictly ascending);
// (b) coalesced div/mod-free xt fill (lane=col, wave-strided rows).

#define LDX12(dst, plane, row, col)                                          \
    { float4 t_;                                                             \
      t_ = *(const float4*)&xt[plane][row][col];                             \
      dst[0]=t_.x; dst[1]=t_.y; dst[2]=t_.z; dst[3]=t_.w;                    \
      t_ = *(const float4*)&xt[plane][row][(col)+4];                         \
      dst[4]=t_.x; dst[5]=t_.y; dst[6]=t_.z; dst[7]=t_.w;                    \
      t_ = *(const float4*)&xt[plane][row][(col)+8];                         \
      dst[8]=t_.x; dst[9]=t_.y; dst[10]=t_.z; dst[11]=t_.w; }

#define C1TAPS(acc0, acc1, acc2, acc3, dp)                                   \
    _Pragma("unroll")                                                        \
    for (int dq = 0; dq < KK; ++dq) {                                        \
        float wa = w1g[(dp) * 7 + dq];                                       \
        float wb = w1g[49 + (dp) * 7 + dq];                                  \
        float wc = w1g[98 + (dp) * 7 + dq];                                  \
        acc0 = __builtin_fmaf(f0[dq + 0], wa, acc0);                         \
        acc0 = __builtin_fmaf(f1[dq + 0], wb, acc0);                         \
        acc0 = __builtin_fmaf(f2[dq + 0], wc, acc0);                         \
        acc1 = __builtin_fmaf(f0[dq + 1], wa, acc1);                         \
        acc1 = __builtin_fmaf(f1[dq + 1], wb, acc1);                         \
        acc1 = __builtin_fmaf(f2[dq + 1], wc, acc1);                         \
        acc2 = __builtin_fmaf(f0[dq + 2], wa, acc2);                         \
        acc2 = __builtin_fmaf(f1[dq + 2], wb, acc2);                         \
        acc2 = __builtin_fmaf(f2[dq + 2], wc, acc2);                         \
        acc3 = __builtin_fmaf(f0[dq + 3], wa, acc3);                         \
        acc3 = __builtin_fmaf(f1[dq + 3], wb, acc3);                         \
        acc3 = __builtin_fmaf(f2[dq + 3], wc, acc3);                         \
    }

__global__ __launch_bounds__(256, 4) void pcanet_fused(
    const float* __restrict__ x,    // (32,3,128,128)
    const float* __restrict__ w1,   // (8,3,7,7)
    const float* __restrict__ w2,   // (8,1,7,7)
    float* __restrict__ out)        // (32, 8*256*64)
{
    const int tid = threadIdx.x;        // 0..255
    const int reg = blockIdx.x;         // 0..15 : 4x4 regions
    const int ch  = blockIdx.y;         // L1 filter index
    const int n   = blockIdx.z;         // image index
    const int P0  = (reg >> 2) * REG;   // region row origin
    const int Q0  = (reg & 3) * REG;    // region col origin

    __shared__ __align__(16) float xt[3][XR][XTP];   // zero-padded x tile
    __shared__ __align__(16) float o1[RT][O1P];      // f32-materialized conv1 tile
    __shared__ int hist[NHB * HSTRIDE];

    const float* __restrict__ w1g = w1 + ch * 147;   // wave-uniform -> s_load
    const float* __restrict__ w2g = w2;              // wave-uniform -> s_load

    // ---- xt fill: lane = tile col (coalesced), rows wave-strided ----
    {
        const int lane = tid & 63;
        const int wv   = tid >> 6;      // 0..3
        const float* xn = x + (size_t)n * 3 * IMG * IMG;
        const int gs = Q0 - 6 + lane;   // global col for this lane
        const bool cok = (lane < XR) && (gs >= 0) && (gs < IMG);
        for (int c = 0; c < 3; ++c)
            for (int r = wv; r < XR; r += 4) {
                int gr = P0 - 6 + r;
                float v = 0.0f;
                if (cok && gr >= 0 && gr < IMG)
                    v = xn[((size_t)c * IMG + gr) * IMG + gs];
                if (lane < XTP) xt[c][r][lane] = v;
            }
    }
    for (int i = tid; i < NHB * HSTRIDE; i += 256) hist[i] = 0;
    __syncthreads();

    // ---- conv1: 19 row-pairs x 10 col-chunks = 190 tasks, single pass ----
    if (tid < 190) {
        int pr = tid / 10;             // row-pair index 0..18
        int c1 = 4 * (tid % 10);       // o1 col base 0..36 (16B-aligned)
        int r0 = 2 * pr;               // o1 rows r0, r0+1
        float a0 = 0.f, a1 = 0.f, a2 = 0.f, a3 = 0.f;   // row r0
        float b0 = 0.f, b1 = 0.f, b2 = 0.f, b3 = 0.f;   // row r0+1
        #pragma unroll
        for (int e = 0; e < 8; ++e) {
            float f0[12], f1[12], f2[12];
            LDX12(f0, 0, r0 + e, c1)
            LDX12(f1, 1, r0 + e, c1)
            LDX12(f2, 2, r0 + e, c1)
            if (e < 7) { C1TAPS(a0, a1, a2, a3, e) }       // row0: dp = e
            if (e >= 1) { C1TAPS(b0, b1, b2, b3, e - 1) }  // row1: dp = e-1
        }
        // mask out-of-image o1 pixels to exact 0 (conv2's zero padding)
        int gs0 = Q0 - 3 + c1;
        bool c0ok = (gs0 + 0 >= 0 && gs0 + 0 < IMG);
        bool c1ok = (gs0 + 1 >= 0 && gs0 + 1 < IMG);
        bool c2ok = (gs0 + 2 >= 0 && gs0 + 2 < IMG);
        bool c3ok = (gs0 + 3 >= 0 && gs0 + 3 < IMG);
        {
            int gr = P0 - 3 + r0;
            bool rok = (gr >= 0 && gr < IMG);
            float4 st;
            st.x = (rok && c0ok) ? a0 : 0.f;
            st.y = (rok && c1ok) ? a1 : 0.f;
            st.z = (rok && c2ok) ? a2 : 0.f;
            st.w = (rok && c3ok) ? a3 : 0.f;
            *(float4*)&o1[r0][c1] = st;
        }
        {
            int gr = P0 - 3 + r0 + 1;
            bool rok = (gr >= 0 && gr < IMG);
            float4 st;
            st.x = (rok && c0ok) ? b0 : 0.f;
            st.y = (rok && c1ok) ? b1 : 0.f;
            st.z = (rok && c2ok) ? b2 : 0.f;
            st.w = (rok && c3ok) ? b3 : 0.f;
            *(float4*)&o1[r0 + 1][c1] = st;
        }
    }
    __syncthreads();

    // ---- conv2: thread owns 4 adjacent pixels (r, c0..c0+3) ----
    {
        const int r  = tid >> 3;          // 0..31 output row in region
        const int c0 = (tid & 7) * 4;     // 0..28 output col base (16B-aligned)
        float acc[NL2][4];
        #pragma unroll
        for (int l = 0; l < NL2; ++l)
            #pragma unroll
            for (int k = 0; k < 4; ++k) acc[l][k] = 0.f;

        for (int dp = 0; dp < KK; ++dp) {
            float f[12];
            { float4 t_;
              t_ = *(const float4*)&o1[r + dp][c0];
              f[0]=t_.x; f[1]=t_.y; f[2]=t_.z; f[3]=t_.w;
              t_ = *(const float4*)&o1[r + dp][c0 + 4];
              f[4]=t_.x; f[5]=t_.y; f[6]=t_.z; f[7]=t_.w;
              t_ = *(const float4*)&o1[r + dp][c0 + 8];
              f[8]=t_.x; f[9]=t_.y; f[10]=t_.z; f[11]=t_.w; }
            #pragma unroll
            for (int l = 0; l < NL2; ++l)
                #pragma unroll
                for (int dq = 0; dq < KK; ++dq) {
                    float w = w2g[l * 49 + dp * 7 + dq];   // uniform scalar
                    acc[l][0] = __builtin_fmaf(f[dq + 0], w, acc[l][0]);
                    acc[l][1] = __builtin_fmaf(f[dq + 1], w, acc[l][1]);
                    acc[l][2] = __builtin_fmaf(f[dq + 2], w, acc[l][2]);
                    acc[l][3] = __builtin_fmaf(f[dq + 3], w, acc[l][3]);
                }
        }
        #pragma unroll
        for (int k = 0; k < 4; ++k) {
            int code = 0;
            #pragma unroll
            for (int l = 0; l < NL2; ++l)
                if (acc[l][k] > 0.0f) code |= (1 << l);
            int bc = (c0 + k) >> 3, br = r >> 3;
            atomicAdd(&hist[(br * 4 + bc) * HSTRIDE + (code >> 2)], 1);
        }
    }
    __syncthreads();

    // ---- write out 16 blocks x 64 bins ----
    size_t planeBase = ((size_t)(n * NL1 + ch)) * 256 * NBINS;
    for (int i = tid; i < NHB * NBINS; i += 256) {
        int bl = i >> 6, bin = i & 63;
        int br = bl >> 2, bc = bl & 3;
        int blkg = ((P0 >> 3) + br) * 16 + ((Q0 >> 3) + bc);
        out[planeBase + (size_t)blkg * NBINS + bin] = (float)hist[bl * HSTRIDE + bin];
    }
}

extern "C" void kernel_launch(void* const* d_in, const int* in_sizes, int n_in,
                              void* d_out, int out_size, void* d_ws, size_t ws_size,
                              hipStream_t stream) {
    const float* x  = (const float*)d_in[0];
    const float* w1 = (const float*)d_in[1];
    const float* w2 = (const float*)d_in[2];
    float* out = (float*)d_out;

    dim3 grid(16, NL1, 32);   // (4x4 regions, 8 L1 channels, 32 images)
    dim3 block(256);
    pcanet_fused<<<grid, block, 0, stream>>>(x, w1, w2, out);
}

// Round 11
// 82.149 us; speedup vs baseline: 5.9197x; 1.1715x over previous
//
#include <hip/hip_runtime.h>
#include <hip/hip_bf16.h>

#define KK 7
#define NL1 8
#define NL2 8
#define IMG 128
#define REG 32            // region edge (pixels) per workgroup
#define RT 38             // o1 tile edge = REG + 6
#define O1P 40            // o1 padded pitch (160B, 16B-aligned; exact fit, reads <= col 39)
#define XR 44             // xt real rows/cols = REG + 12
#define XTP 44            // xt pitch = 44 (176B, 16B-aligned; exact fit, real reads <= col 43)
#define NBINS 64
#define NHB 16            // histogram blocks per region (4x4 of 8x8)

// Correctness contract (matches XLA-CPU f32 reference, verified round 6):
//  conv1: per-pixel strict sequential FMA chain, taps ordered dp->dq->c(fastest)
//  out1 : materialized as f32 (and zeroed outside the image = conv2 padding)
//  conv2: per-filter strict sequential FMA chain, taps ordered dp->dq
// Restructuring only changes WHERE operands come from, never per-chain order.
//
// Round-11: LDS 38.4KB -> 31.4KB (xt pitch 52->44, o1 pitch 44->40, histogram
// packed to 16-bit halfwords) => 5 blocks/CU instead of 4 (62.5% occupancy
// cap), attacking the latency-bound regime (both VALU 50% and LDS ~25% idle).
// NOTE: conv1's 12-wide LDX12 over-reads cols 44..47 of a row; those elements
// land in f[10..11] or feed only o1 pad columns 38/39 — never consumed — and
// stay inside this block's LDS allocation. Max count/bin = 64 << 2^16 so the
// packed halfword atomicAdd can never carry into the neighbor bin.

#define LDX12(dst, plane, row, col)                                          \
    { float4 t_;                                                             \
      t_ = *(const float4*)&xt[plane][row][col];                             \
      dst[0]=t_.x; dst[1]=t_.y; dst[2]=t_.z; dst[3]=t_.w;                    \
      t_ = *(const float4*)&xt[plane][row][(col)+4];                         \
      dst[4]=t_.x; dst[5]=t_.y; dst[6]=t_.z; dst[7]=t_.w;                    \
      t_ = *(const float4*)&xt[plane][row][(col)+8];                         \
      dst[8]=t_.x; dst[9]=t_.y; dst[10]=t_.z; dst[11]=t_.w; }

#define C1TAPS(acc0, acc1, acc2, acc3, dp)                                   \
    _Pragma("unroll")                                                        \
    for (int dq = 0; dq < KK; ++dq) {                                        \
        float wa = w1g[(dp) * 7 + dq];                                       \
        float wb = w1g[49 + (dp) * 7 + dq];                                  \
        float wc = w1g[98 + (dp) * 7 + dq];                                  \
        acc0 = __builtin_fmaf(f0[dq + 0], wa, acc0);                         \
        acc0 = __builtin_fmaf(f1[dq + 0], wb, acc0);                         \
        acc0 = __builtin_fmaf(f2[dq + 0], wc, acc0);                         \
        acc1 = __builtin_fmaf(f0[dq + 1], wa, acc1);                         \
        acc1 = __builtin_fmaf(f1[dq + 1], wb, acc1);                         \
        acc1 = __builtin_fmaf(f2[dq + 1], wc, acc1);                         \
        acc2 = __builtin_fmaf(f0[dq + 2], wa, acc2);                         \
        acc2 = __builtin_fmaf(f1[dq + 2], wb, acc2);                         \
        acc2 = __builtin_fmaf(f2[dq + 2], wc, acc2);                         \
        acc3 = __builtin_fmaf(f0[dq + 3], wa, acc3);                         \
        acc3 = __builtin_fmaf(f1[dq + 3], wb, acc3);                         \
        acc3 = __builtin_fmaf(f2[dq + 3], wc, acc3);                         \
    }

__global__ __launch_bounds__(256, 5) void pcanet_fused(
    const float* __restrict__ x,    // (32,3,128,128)
    const float* __restrict__ w1,   // (8,3,7,7)
    const float* __restrict__ w2,   // (8,1,7,7)
    float* __restrict__ out)        // (32, 8*256*64)
{
    const int tid = threadIdx.x;        // 0..255
    const int reg = blockIdx.x;         // 0..15 : 4x4 regions
    const int ch  = blockIdx.y;         // L1 filter index
    const int n   = blockIdx.z;         // image index
    const int P0  = (reg >> 2) * REG;   // region row origin
    const int Q0  = (reg & 3) * REG;    // region col origin

    __shared__ __align__(16) float xt[3][XR][XTP];   // zero-padded x tile (23.2KB)
    __shared__ __align__(16) float o1[RT][O1P];      // f32 conv1 tile (6.1KB)
    __shared__ unsigned int hist[NHB * 32];          // 16 blocks x 64 bins packed u16 (2KB)

    const float* __restrict__ w1g = w1 + ch * 147;   // wave-uniform -> s_load
    const float* __restrict__ w2g = w2;              // wave-uniform -> s_load

    // ---- xt fill: lane = tile col (coalesced), rows wave-strided ----
    {
        const int lane = tid & 63;
        const int wv   = tid >> 6;      // 0..3
        const float* xn = x + (size_t)n * 3 * IMG * IMG;
        const int gs = Q0 - 6 + lane;   // global col for this lane
        const bool cok = (gs >= 0) && (gs < IMG);
        if (lane < XTP) {
            for (int c = 0; c < 3; ++c)
                for (int r = wv; r < XR; r += 4) {
                    int gr = P0 - 6 + r;
                    float v = 0.0f;
                    if (cok && gr >= 0 && gr < IMG)
                        v = xn[((size_t)c * IMG + gr) * IMG + gs];
                    xt[c][r][lane] = v;
                }
        }
    }
    for (int i = tid; i < NHB * 32; i += 256) hist[i] = 0u;
    __syncthreads();

    // ---- conv1: 19 row-pairs x 10 col-chunks = 190 tasks, single pass ----
    if (tid < 190) {
        int pr = tid / 10;             // row-pair index 0..18
        int c1 = 4 * (tid % 10);       // o1 col base 0..36 (16B-aligned)
        int r0 = 2 * pr;               // o1 rows r0, r0+1
        float a0 = 0.f, a1 = 0.f, a2 = 0.f, a3 = 0.f;   // row r0
        float b0 = 0.f, b1 = 0.f, b2 = 0.f, b3 = 0.f;   // row r0+1
        #pragma unroll
        for (int e = 0; e < 8; ++e) {
            float f0[12], f1[12], f2[12];
            LDX12(f0, 0, r0 + e, c1)
            LDX12(f1, 1, r0 + e, c1)
            LDX12(f2, 2, r0 + e, c1)
            if (e < 7) { C1TAPS(a0, a1, a2, a3, e) }       // row0: dp = e
            if (e >= 1) { C1TAPS(b0, b1, b2, b3, e - 1) }  // row1: dp = e-1
        }
        // mask out-of-image o1 pixels to exact 0 (conv2's zero padding)
        int gs0 = Q0 - 3 + c1;
        bool c0ok = (gs0 + 0 >= 0 && gs0 + 0 < IMG);
        bool c1ok = (gs0 + 1 >= 0 && gs0 + 1 < IMG);
        bool c2ok = (gs0 + 2 >= 0 && gs0 + 2 < IMG);
        bool c3ok = (gs0 + 3 >= 0 && gs0 + 3 < IMG);
        {
            int gr = P0 - 3 + r0;
            bool rok = (gr >= 0 && gr < IMG);
            float4 st;
            st.x = (rok && c0ok) ? a0 : 0.f;
            st.y = (rok && c1ok) ? a1 : 0.f;
            st.z = (rok && c2ok) ? a2 : 0.f;
            st.w = (rok && c3ok) ? a3 : 0.f;
            *(float4*)&o1[r0][c1] = st;
        }
        {
            int gr = P0 - 3 + r0 + 1;
            bool rok = (gr >= 0 && gr < IMG);
            float4 st;
            st.x = (rok && c0ok) ? b0 : 0.f;
            st.y = (rok && c1ok) ? b1 : 0.f;
            st.z = (rok && c2ok) ? b2 : 0.f;
            st.w = (rok && c3ok) ? b3 : 0.f;
            *(float4*)&o1[r0 + 1][c1] = st;
        }
    }
    __syncthreads();

    // ---- conv2: thread owns 4 adjacent pixels (r, c0..c0+3) ----
    {
        const int r  = tid >> 3;          // 0..31 output row in region
        const int c0 = (tid & 7) * 4;     // 0..28 output col base (16B-aligned)
        float acc[NL2][4];
        #pragma unroll
        for (int l = 0; l < NL2; ++l)
            #pragma unroll
            for (int k = 0; k < 4; ++k) acc[l][k] = 0.f;

        for (int dp = 0; dp < KK; ++dp) {
            float f[12];
            { float4 t_;
              t_ = *(const float4*)&o1[r + dp][c0];
              f[0]=t_.x; f[1]=t_.y; f[2]=t_.z; f[3]=t_.w;
              t_ = *(const float4*)&o1[r + dp][c0 + 4];
              f[4]=t_.x; f[5]=t_.y; f[6]=t_.z; f[7]=t_.w;
              t_ = *(const float4*)&o1[r + dp][c0 + 8];
              f[8]=t_.x; f[9]=t_.y; f[10]=t_.z; f[11]=t_.w; }
            #pragma unroll
            for (int l = 0; l < NL2; ++l)
                #pragma unroll
                for (int dq = 0; dq < KK; ++dq) {
                    float w = w2g[l * 49 + dp * 7 + dq];   // uniform scalar
                    acc[l][0] = __builtin_fmaf(f[dq + 0], w, acc[l][0]);
                    acc[l][1] = __builtin_fmaf(f[dq + 1], w, acc[l][1]);
                    acc[l][2] = __builtin_fmaf(f[dq + 2], w, acc[l][2]);
                    acc[l][3] = __builtin_fmaf(f[dq + 3], w, acc[l][3]);
                }
        }
        #pragma unroll
        for (int k = 0; k < 4; ++k) {
            int code = 0;
            #pragma unroll
            for (int l = 0; l < NL2; ++l)
                if (acc[l][k] > 0.0f) code |= (1 << l);
            int bin = code >> 2;                       // 0..63
            int bc = (c0 + k) >> 3, br = r >> 3;
            atomicAdd(&hist[(br * 4 + bc) * 32 + (bin >> 1)],
                      1u << (16 * (bin & 1)));
        }
    }
    __syncthreads();

    // ---- write out 16 blocks x 64 bins (unpack halfwords) ----
    size_t planeBase = ((size_t)(n * NL1 + ch)) * 256 * NBINS;
    for (int i = tid; i < NHB * NBINS; i += 256) {
        int bl = i >> 6, bin = i & 63;
        unsigned int w = hist[bl * 32 + (bin >> 1)];
        unsigned int cnt = (w >> (16 * (bin & 1))) & 0xFFFFu;
        int br = bl >> 2, bc = bl & 3;
        int blkg = ((P0 >> 3) + br) * 16 + ((Q0 >> 3) + bc);
        out[planeBase + (size_t)blkg * NBINS + bin] = (float)cnt;
    }
}

extern "C" void kernel_launch(void* const* d_in, const int* in_sizes, int n_in,
                              void* d_out, int out_size, void* d_ws, size_t ws_size,
                              hipStream_t stream) {
    const float* x  = (const float*)d_in[0];
    const float* w1 = (const float*)d_in[1];
    const float* w2 = (const float*)d_in[2];
    float* out = (float*)d_out;

    dim3 grid(16, NL1, 32);   // (4x4 regions, 8 L1 channels, 32 images)
    dim3 block(256);
    pcanet_fused<<<grid, block, 0, stream>>>(x, w1, w2, out);
}